// Round 6
// baseline (3689.294 us; speedup 1.0000x reference)
//
#include <hip/hip_runtime.h>
#include <hip/hip_bf16.h>

// GRU recurrence B=128, S=512, H=1024 — persistent kernel, IC-coherent exchange
// (sc0 sc1 everywhere for cross-WG data; the r4-proven semantics).
// 8 independent groups x 32 WGs (group = wg&7); group owns 16 batch rows; WG
// owns 32 cols; weights in registers (layout verified r3/r4).
// Round-6 deltas vs r4: (1) barrier arrival = fire-and-forget system-scope
// atomic add to ONE per-group counter (no slot array, no ack wait);
// (2) poll = single-word IC load by ALL waves independently (no wave-0 poll +
// syncthreads fan-out); (3) out-stores + emb prefetches in post-arrive shadow.

#define Ss 512
#define Hh 1024
#define NWG 256
#define NTHR 512

typedef __bf16 bf16x8 __attribute__((ext_vector_type(8)));
typedef float f32x4 __attribute__((ext_vector_type(4)));
typedef int   i32x4 __attribute__((ext_vector_type(4)));

__device__ __forceinline__ float sigmoid_fast(float x) { return 1.0f / (1.0f + __expf(-x)); }
__device__ __forceinline__ float tanh_fast(float x) { return 2.0f / (1.0f + __expf(-2.0f * x)) - 1.0f; }

// ---- IC-coherent (sc0 sc1) access helpers ----
__device__ __forceinline__ void ic_store_bf16(__bf16* p, float v) {
    unsigned u = (unsigned)__builtin_bit_cast(unsigned short, (__bf16)v);
    asm volatile("global_store_short %0, %1, off sc0 sc1" :: "v"(p), "v"(u) : "memory");
}
__device__ __forceinline__ unsigned ic_load_u32(const unsigned* p) {
    unsigned v;
    asm volatile("global_load_dword %0, %1, off sc0 sc1\n\ts_waitcnt vmcnt(0)"
                 : "=v"(v) : "v"(p) : "memory");
    return v;
}

// stage a [16 x 1024] bf16 tile (row stride 2048B) from IC into LDS, swizzled
__device__ __forceinline__ void stage16rows(const char* g, char* stbuf, int tid) {
    int c0 = tid, c1 = tid + 512, c2 = tid + 1024, c3 = tid + 1536;
    const void* a0 = g + (c0 >> 7) * 2048 + (c0 & 127) * 16;
    const void* a1 = g + (c1 >> 7) * 2048 + (c1 & 127) * 16;
    const void* a2 = g + (c2 >> 7) * 2048 + (c2 & 127) * 16;
    const void* a3 = g + (c3 >> 7) * 2048 + (c3 & 127) * 16;
    i32x4 r0, r1, r2, r3;
    asm volatile(
        "global_load_dwordx4 %0, %4, off sc0 sc1\n\t"
        "global_load_dwordx4 %1, %5, off sc0 sc1\n\t"
        "global_load_dwordx4 %2, %6, off sc0 sc1\n\t"
        "global_load_dwordx4 %3, %7, off sc0 sc1\n\t"
        "s_waitcnt vmcnt(0)"
        : "=&v"(r0), "=&v"(r1), "=&v"(r2), "=&v"(r3)
        : "v"(a0), "v"(a1), "v"(a2), "v"(a3));
    *(i32x4*)(stbuf + (c0 >> 7) * 2048 + (((c0 & 127) * 16) ^ (((c0 >> 7) & 7) << 4))) = r0;
    *(i32x4*)(stbuf + (c1 >> 7) * 2048 + (((c1 & 127) * 16) ^ (((c1 >> 7) & 7) << 4))) = r1;
    *(i32x4*)(stbuf + (c2 >> 7) * 2048 + (((c2 & 127) * 16) ^ (((c2 >> 7) & 7) << 4))) = r2;
    *(i32x4*)(stbuf + (c3 >> 7) * 2048 + (((c3 & 127) * 16) ^ (((c3 >> 7) & 7) << 4))) = r3;
}

__device__ __forceinline__ bf16x8 frag(const char* stbuf, int row, int kelem) {
    return *(const bf16x8*)(stbuf + row * 2048 + ((kelem * 2) ^ ((row & 7) << 4)));
}

// arrive: drain my IC stores (ack), block-sync, one lane bumps group counter.
// Fire-and-forget add: no return value -> no wait on the RMW.
__device__ __forceinline__ void arrive(unsigned* cnt, int tid) {
    asm volatile("s_waitcnt vmcnt(0)" ::: "memory");
    __syncthreads();
    if (tid == 0)
        (void)__hip_atomic_fetch_add(cnt, 1u, __ATOMIC_RELAXED, __HIP_MEMORY_SCOPE_SYSTEM);
}
// wait: every wave spins on the single counter word at the IC (self-pacing).
__device__ __forceinline__ void pollwait(const unsigned* cnt, unsigned target) {
    while (ic_load_u32(cnt) < target) { }
}

__global__ __launch_bounds__(NTHR, 2) void gru_v6(
    const float* __restrict__ emb, const float* __restrict__ Ww,
    const float* __restrict__ Wb, const float* __restrict__ Uw,
    const float* __restrict__ Ub, const float* __restrict__ Vw,
    const float* __restrict__ Vb,
    __bf16* __restrict__ pxi, __bf16* __restrict__ av,
    unsigned* __restrict__ arr, float* __restrict__ out)
{
    __shared__ char  stbuf[32768];
    __shared__ f32x4 sc[6][64];
    __shared__ float p_lds[16][32];

    const int tid   = threadIdx.x;
    const int lane  = tid & 63;
    const int wid   = tid >> 6;          // 0..7
    const int la    = lane & 15;
    const int lb    = lane >> 4;
    const int wg    = blockIdx.x;
    const int g     = wg & 7;            // group
    const int lw    = wg >> 3;           // 0..31 within group
    const int rbase = g * 16;            // group's 16 batch rows
    const int n0    = lw * 32;           // WG's 32 output cols
    const int nt    = wid & 1;           // n-tile (16 cols)
    const int kh    = (wid >> 1) & 1;    // phase A K-half
    const int kq    = wid >> 1;          // phase B K-quarter
    const int jc    = n0 + nt * 16 + la;
    unsigned* cnt   = arr + g * 64;      // one counter per group, 256B stride

    // ---- weights -> registers (one-time; layout verified r3/r4) ----
    const float* WA = (wid < 4) ? Ww : Uw;
    bf16x8 Wa[16];
#pragma unroll
    for (int i = 0; i < 16; ++i) {
        const float* s = WA + (size_t)jc * Hh + kh * 512 + i * 32 + lb * 8;
        bf16x8 v;
#pragma unroll
        for (int j = 0; j < 8; ++j) v[j] = (__bf16)s[j];
        Wa[i] = v;
    }
    bf16x8 Vf[8];
#pragma unroll
    for (int i = 0; i < 8; ++i) {
        const float* s = Vw + (size_t)jc * Hh + kq * 256 + i * 32 + lb * 8;
        bf16x8 v;
#pragma unroll
        for (int j = 0; j < 8; ++j) v[j] = (__bf16)s[j];
        Vf[i] = v;
    }
    const float bias1 = (wid < 4) ? Wb[jc] : Ub[jc];
    const float bias2 = Vb[jc];

    // ---- init: p=0 (regs + LDS mirror), pxi0 = bf16(x_0) via IC stores ----
    ((float*)p_lds)[tid] = 0.0f;
    f32x4 pregs = {0.f, 0.f, 0.f, 0.f};
    if (wid == 4 || wid == 5) {
#pragma unroll
        for (int r = 0; r < 4; ++r) {
            int row = rbase + lb * 4 + r;
            ic_store_bf16(pxi + row * Hh + jc, emb[(size_t)row * (Ss * Hh) + jc]);
        }
    }
    // first-iteration embc preload (waves 0,1)
    f32x4 embc = {0.f, 0.f, 0.f, 0.f};
    if (wid == 0 || wid == 1) {
#pragma unroll
        for (int r = 0; r < 4; ++r)
            embc[r] = emb[((size_t)(rbase + lb * 4 + r) * Ss + 0) * Hh + jc];
    }
    unsigned ph = 1;
    arrive(cnt, tid);

    const char* pxiG = (const char*)(pxi + (size_t)rbase * Hh);
    const char* avG  = (const char*)(av  + (size_t)rbase * Hh);

    for (int t = 0; t < Ss; ++t) {
        // ---- phase A: wait pxi(t), stage -> LDS, GEMM (r: wid0-3, z: wid4-7) ----
        pollwait(cnt, ph * 32u);
        stage16rows(pxiG, stbuf, tid);
        __syncthreads();
        f32x4 acc0 = {0.f, 0.f, 0.f, 0.f}, acc1 = acc0;
#pragma unroll
        for (int i = 0; i < 8; ++i) {
            bf16x8 a0 = frag(stbuf, la, kh * 512 + (2 * i) * 32 + lb * 8);
            bf16x8 a1 = frag(stbuf, la, kh * 512 + (2 * i + 1) * 32 + lb * 8);
            acc0 = __builtin_amdgcn_mfma_f32_16x16x32_bf16(a0, Wa[2 * i],     acc0, 0, 0, 0);
            acc1 = __builtin_amdgcn_mfma_f32_16x16x32_bf16(a1, Wa[2 * i + 1], acc1, 0, 0, 0);
        }
        f32x4 acc = acc0 + acc1;
        if (kh == 1) sc[(wid < 4 ? 0 : 2) + nt][lane] = acc;
        __syncthreads();
        f32x4 zz = {0.f, 0.f, 0.f, 0.f};
        if (wid == 0 || wid == 1) {          // r-finalize -> av (IC store)
            acc += sc[nt][lane];
#pragma unroll
            for (int r = 0; r < 4; ++r) {
                int row = rbase + lb * 4 + r;
                float rg = sigmoid_fast(acc[r] + bias1);
                float pc = p_lds[lb * 4 + r][nt * 16 + la];
                ic_store_bf16(av + row * Hh + jc, rg * pc + embc[r]);
            }
        } else if (wid == 4 || wid == 5) {   // z-finalize -> registers
            acc += sc[2 + nt][lane];
#pragma unroll
            for (int r = 0; r < 4; ++r) zz[r] = sigmoid_fast(acc[r] + bias1);
        }
        arrive(cnt, tid); ++ph;              // publish av

        // shadow window: next-step emb for pxi update (waves 4,5)
        f32x4 embn = {0.f, 0.f, 0.f, 0.f};
        if ((wid == 4 || wid == 5) && t + 1 < Ss) {
#pragma unroll
            for (int r = 0; r < 4; ++r)
                embn[r] = emb[((size_t)(rbase + lb * 4 + r) * Ss + (t + 1)) * Hh + jc];
        }

        // ---- phase B: wait av, stage -> LDS, h-GEMM (all waves, K-quarter) ----
        pollwait(cnt, ph * 32u);
        stage16rows(avG, stbuf, tid);
        __syncthreads();
        f32x4 h0 = {0.f, 0.f, 0.f, 0.f}, h1 = h0;
#pragma unroll
        for (int i = 0; i < 4; ++i) {
            bf16x8 a0 = frag(stbuf, la, kq * 256 + (2 * i) * 32 + lb * 8);
            bf16x8 a1 = frag(stbuf, la, kq * 256 + (2 * i + 1) * 32 + lb * 8);
            h0 = __builtin_amdgcn_mfma_f32_16x16x32_bf16(a0, Vf[2 * i],     h0, 0, 0, 0);
            h1 = __builtin_amdgcn_mfma_f32_16x16x32_bf16(a1, Vf[2 * i + 1], h1, 0, 0, 0);
        }
        f32x4 hacc = h0 + h1;
        if (wid != 4 && wid != 5)
            sc[nt * 3 + (kq == 0 ? 0 : (kq == 1 ? 1 : 2))][lane] = hacc;
        __syncthreads();
        f32x4 pn = {0.f, 0.f, 0.f, 0.f};
        if (wid == 4 || wid == 5) {          // h-finalize + gate combine
            int base = nt * 3;
            hacc += sc[base][lane] + sc[base + 1][lane] + sc[base + 2][lane];
#pragma unroll
            for (int r = 0; r < 4; ++r) {
                int row  = rbase + lb * 4 + r;
                float h  = tanh_fast(hacc[r] + bias2);
                pn[r] = (1.0f - zz[r]) * pregs[r] + zz[r] * h;
                pregs[r] = pn[r];
                p_lds[lb * 4 + r][nt * 16 + la] = pn[r];
                if (t + 1 < Ss)
                    ic_store_bf16(pxi + row * Hh + jc, pn[r] + embn[r]);
            }
        }
        if (t + 1 < Ss) { arrive(cnt, tid); ++ph; }   // publish pxi(t+1)

        // shadow window: out-store (cached, no reader) + embc for t+1
        if (wid == 4 || wid == 5) {
#pragma unroll
            for (int r = 0; r < 4; ++r)
                out[((size_t)(rbase + lb * 4 + r) * Ss + t) * Hh + jc] = pn[r];
        }
        if ((wid == 0 || wid == 1) && t + 1 < Ss) {
#pragma unroll
            for (int r = 0; r < 4; ++r)
                embc[r] = emb[((size_t)(rbase + lb * 4 + r) * Ss + (t + 1)) * Hh + jc];
        }
    }
}

// ---- launch -----------------------------------------------------------------

extern "C" void kernel_launch(void* const* d_in, const int* in_sizes, int n_in,
                              void* d_out, int out_size, void* d_ws, size_t ws_size,
                              hipStream_t stream) {
    const float* emb = (const float*)d_in[0];
    const float* Ww  = (const float*)d_in[1];
    const float* Wb  = (const float*)d_in[2];
    const float* Uw  = (const float*)d_in[3];
    const float* Ub  = (const float*)d_in[4];
    const float* Vw  = (const float*)d_in[5];
    const float* Vb  = (const float*)d_in[6];
    float* out = (float*)d_out;

    char* ws = (char*)d_ws;
    __bf16*   pxi = (__bf16*)(ws);                     // 256 KB
    __bf16*   av  = (__bf16*)(ws + 256 * 1024);        // 256 KB
    unsigned* arr = (unsigned*)(ws + 512 * 1024);      // 8 counters x 256B

    hipMemsetAsync(arr, 0, 4096, stream);

    void* args[] = {(void*)&emb, (void*)&Ww, (void*)&Wb, (void*)&Uw, (void*)&Ub,
                    (void*)&Vw, (void*)&Vb, (void*)&pxi, (void*)&av,
                    (void*)&arr, (void*)&out};
    hipError_t e = hipLaunchCooperativeKernel(
        reinterpret_cast<const void*>(gru_v6), dim3(NWG), dim3(NTHR),
        args, 0, stream);
    if (e != hipSuccess) {
        gru_v6<<<dim3(NWG), dim3(NTHR), 0, stream>>>(
            emb, Ww, Wb, Uw, Ub, Vw, Vb, pxi, av, arr, out);
    }
}